// Round 1
// baseline (1860.152 us; speedup 1.0000x reference)
//
#include <hip/hip_runtime.h>
#include <math.h>

// Problem constants
#define B_ 4
#define L_ 8192
#define D_ 1024
#define M_ (B_ * L_)   // 32768 rows of x flattened
#define K_ D_          // 1024 reduction dim

// GEMM tiling
#define BM 128
#define BN 128
#define BK 16

// Scan chunking
#define NC 128
#define CHUNK (L_ / NC)  // 64

// ---------------------------------------------------------------------------
// Kernel 1: fused dual GEMM + activation.
//   g[b,l,e] = sigmoid( sum_d x[b,l,d] * Wg[e,d] + bg[e] )
//   c[b,l,e] = tanh   ( sum_d x[b,l,d] * Wc[e,d] + bc[e] )
// grid.x = M_/BM (256) m-tiles; grid.y = 16: y<8 -> Wg tiles, y>=8 -> Wc tiles.
// fp32 vector GEMM: 128x128 tile, BK=16, 256 threads, 8x8 micro-tile.
// ---------------------------------------------------------------------------
__global__ __launch_bounds__(256) void gemm_act_kernel(
    const float* __restrict__ X,
    const float* __restrict__ Wg, const float* __restrict__ bg,
    const float* __restrict__ Wc, const float* __restrict__ bc,
    float* __restrict__ g_ws, float* __restrict__ c_ws)
{
    __shared__ float As[BK][BM];
    __shared__ float Bs[BK][BN];

    const int t = threadIdx.x;
    const int mblk = blockIdx.x;
    const int nblk = blockIdx.y;
    const bool isGate = (nblk < 8);
    const float* __restrict__ W    = isGate ? Wg : Wc;
    const float* __restrict__ bias = isGate ? bg : bc;
    float* __restrict__ outp       = isGate ? g_ws : c_ws;
    const int n0 = (nblk & 7) * BN;   // channel base within D
    const int m0 = mblk * BM;

    // Global->LDS staging: each thread loads 8 contiguous floats of one row.
    const int arow = t >> 1;          // 0..127
    const int acol = (t & 1) * 8;     // 0 or 8
    const float* Aptr = X + (size_t)(m0 + arow) * K_ + acol;
    const float* Bptr = W + (size_t)(n0 + arow) * K_ + acol;

    const int tx = t & 15;            // 16 thread cols
    const int ty = t >> 4;            // 16 thread rows

    float acc[8][8];
#pragma unroll
    for (int i = 0; i < 8; ++i)
#pragma unroll
        for (int j = 0; j < 8; ++j) acc[i][j] = 0.f;

    for (int k0 = 0; k0 < K_; k0 += BK) {
        float4 a0 = *(const float4*)(Aptr + k0);
        float4 a1 = *(const float4*)(Aptr + k0 + 4);
        float4 b0 = *(const float4*)(Bptr + k0);
        float4 b1 = *(const float4*)(Bptr + k0 + 4);
        __syncthreads();   // previous tile fully consumed
        // transpose into LDS: As[k][m], Bs[k][n]; bank = arow%32 -> 2-way (free)
        As[acol + 0][arow] = a0.x; As[acol + 1][arow] = a0.y;
        As[acol + 2][arow] = a0.z; As[acol + 3][arow] = a0.w;
        As[acol + 4][arow] = a1.x; As[acol + 5][arow] = a1.y;
        As[acol + 6][arow] = a1.z; As[acol + 7][arow] = a1.w;
        Bs[acol + 0][arow] = b0.x; Bs[acol + 1][arow] = b0.y;
        Bs[acol + 2][arow] = b0.z; Bs[acol + 3][arow] = b0.w;
        Bs[acol + 4][arow] = b1.x; Bs[acol + 5][arow] = b1.y;
        Bs[acol + 6][arow] = b1.z; Bs[acol + 7][arow] = b1.w;
        __syncthreads();
#pragma unroll
        for (int kk = 0; kk < BK; ++kk) {
            float af[8], bf[8];
            *(float4*)&af[0] = *(const float4*)&As[kk][ty * 8];
            *(float4*)&af[4] = *(const float4*)&As[kk][ty * 8 + 4];
            *(float4*)&bf[0] = *(const float4*)&Bs[kk][tx * 8];
            *(float4*)&bf[4] = *(const float4*)&Bs[kk][tx * 8 + 4];
#pragma unroll
            for (int i = 0; i < 8; ++i)
#pragma unroll
                for (int j = 0; j < 8; ++j)
                    acc[i][j] = fmaf(af[i], bf[j], acc[i][j]);
        }
    }

    float bj[8];
#pragma unroll
    for (int j = 0; j < 8; ++j) bj[j] = bias[n0 + tx * 8 + j];

#pragma unroll
    for (int i = 0; i < 8; ++i) {
        const int m = m0 + ty * 8 + i;
        float* rp = outp + (size_t)m * D_ + n0 + tx * 8;
        float v[8];
#pragma unroll
        for (int j = 0; j < 8; ++j) {
            float z = acc[i][j] + bj[j];
            // isGate is wave-uniform (whole block) -> no divergence
            v[j] = isGate ? (1.f / (1.f + expf(-z))) : tanhf(z);
        }
        *(float4*)rp       = make_float4(v[0], v[1], v[2], v[3]);
        *(float4*)(rp + 4) = make_float4(v[4], v[5], v[6], v[7]);
    }
}

// ---------------------------------------------------------------------------
// Kernel 2: per-chunk local scan -> chunk carry (A = prod g, Bv = local h end)
// grid = (NC, B_); 256 threads; each thread owns 4 contiguous channels (float4)
// ---------------------------------------------------------------------------
__global__ __launch_bounds__(256) void scan_phase1(
    const float* __restrict__ g_ws, const float* __restrict__ c_ws,
    float* __restrict__ carryA, float* __restrict__ carryB)
{
    const int t = threadIdx.x;
    const int cid = blockIdx.x;   // chunk
    const int b   = blockIdx.y;
    const size_t base = ((size_t)b * L_ + (size_t)cid * CHUNK) * D_;
    const float4* g4 = (const float4*)(g_ws + base) + t;
    const float4* c4 = (const float4*)(c_ws + base) + t;

    float4 A  = make_float4(1.f, 1.f, 1.f, 1.f);
    float4 Bv = make_float4(0.f, 0.f, 0.f, 0.f);
#pragma unroll 4
    for (int l = 0; l < CHUNK; ++l) {
        float4 g = g4[(size_t)l * (D_ / 4)];
        float4 c = c4[(size_t)l * (D_ / 4)];
        Bv.x = fmaf(g.x, Bv.x, c.x); Bv.y = fmaf(g.y, Bv.y, c.y);
        Bv.z = fmaf(g.z, Bv.z, c.z); Bv.w = fmaf(g.w, Bv.w, c.w);
        A.x *= g.x; A.y *= g.y; A.z *= g.z; A.w *= g.w;
    }
    const size_t cbase = ((size_t)b * NC + cid) * D_;
    ((float4*)(carryA + cbase))[t] = A;
    ((float4*)(carryB + cbase))[t] = Bv;
}

// ---------------------------------------------------------------------------
// Kernel 3: exclusive scan of chunk carries along NC per channel.
// Overwrites carryB[k] with h_in for chunk k (h before the chunk; h0 = 0).
// One thread per (b,d) channel: 4096 threads = 16 blocks.
// ---------------------------------------------------------------------------
__global__ __launch_bounds__(256) void scan_phase2(
    const float* __restrict__ carryA, float* __restrict__ carryB)
{
    const int idx = blockIdx.x * 256 + threadIdx.x;  // 0 .. B_*D_-1
    const int b = idx >> 10;
    const int d = idx & (D_ - 1);
    float accB = 0.f;
    for (int k = 0; k < NC; ++k) {
        const size_t o = ((size_t)b * NC + k) * D_ + d;
        const float a  = carryA[o];
        const float bb = carryB[o];
        carryB[o] = accB;            // h entering chunk k
        accB = fmaf(a, accB, bb);
    }
}

// ---------------------------------------------------------------------------
// Kernel 4: re-scan each chunk with its incoming h, write final output.
// ---------------------------------------------------------------------------
__global__ __launch_bounds__(256) void scan_phase3(
    const float* __restrict__ g_ws, const float* __restrict__ c_ws,
    const float* __restrict__ carryB, float* __restrict__ out)
{
    const int t = threadIdx.x;
    const int cid = blockIdx.x;
    const int b   = blockIdx.y;
    const size_t base = ((size_t)b * L_ + (size_t)cid * CHUNK) * D_;
    const float4* g4 = (const float4*)(g_ws + base) + t;
    const float4* c4 = (const float4*)(c_ws + base) + t;
    float4* o4 = (float4*)(out + base) + t;

    const size_t cbase = ((size_t)b * NC + cid) * D_;
    float4 h = ((const float4*)(carryB + cbase))[t];
#pragma unroll 4
    for (int l = 0; l < CHUNK; ++l) {
        float4 g = g4[(size_t)l * (D_ / 4)];
        float4 c = c4[(size_t)l * (D_ / 4)];
        h.x = fmaf(g.x, h.x, c.x); h.y = fmaf(g.y, h.y, c.y);
        h.z = fmaf(g.z, h.z, c.z); h.w = fmaf(g.w, h.w, c.w);
        o4[(size_t)l * (D_ / 4)] = h;
    }
}

// ---------------------------------------------------------------------------
extern "C" void kernel_launch(void* const* d_in, const int* in_sizes, int n_in,
                              void* d_out, int out_size, void* d_ws, size_t ws_size,
                              hipStream_t stream)
{
    const float* x  = (const float*)d_in[0];
    const float* Wg = (const float*)d_in[1];
    const float* bg = (const float*)d_in[2];
    const float* Wc = (const float*)d_in[3];
    const float* bc = (const float*)d_in[4];
    float* out = (float*)d_out;

    // Workspace layout (fp32):
    //   g_ws   : M_*D_            (134.2 MB)
    //   c_ws   : M_*D_            (134.2 MB)
    //   carryA : B_*NC*D_         (2 MB)
    //   carryB : B_*NC*D_         (2 MB)
    float* ws = (float*)d_ws;
    float* g_ws   = ws;
    float* c_ws   = g_ws + (size_t)M_ * D_;
    float* carryA = c_ws + (size_t)M_ * D_;
    float* carryB = carryA + (size_t)B_ * NC * D_;

    dim3 ggrid(M_ / BM, 16);
    gemm_act_kernel<<<ggrid, 256, 0, stream>>>(x, Wg, bg, Wc, bc, g_ws, c_ws);

    scan_phase1<<<dim3(NC, B_), 256, 0, stream>>>(g_ws, c_ws, carryA, carryB);
    scan_phase2<<<(B_ * D_) / 256, 256, 0, stream>>>(carryA, carryB);
    scan_phase3<<<dim3(NC, B_), 256, 0, stream>>>(g_ws, c_ws, carryB, out);
}

// Round 2
// 837.623 us; speedup vs baseline: 2.2208x; 2.2208x over previous
//
#include <hip/hip_runtime.h>
#include <math.h>

// Problem constants
#define B_ 4
#define L_ 8192
#define D_ 1024
#define M_ (B_ * L_)   // 32768 rows
#define K_ D_          // 1024 reduction dim

// GEMM tiling (m97 recipe: 128x128 tile, BK=32, 4 waves, 16x16x32 MFMA)
#define BM 128
#define BN 128
#define BK 32

// Scan chunking
#define NC 128
#define CHUNK (L_ / NC)  // 64

typedef short bf16x8 __attribute__((ext_vector_type(8)));
typedef float f32x4 __attribute__((ext_vector_type(4)));

__device__ __forceinline__ unsigned short f2bf(float f) {
    unsigned u = __float_as_uint(f);
    u += 0x7fff + ((u >> 16) & 1);   // RNE
    return (unsigned short)(u >> 16);
}
__device__ __forceinline__ float bf2f(unsigned short h) {
    return __uint_as_float(((unsigned)h) << 16);
}

__device__ __forceinline__ void async16(const void* g, void* l) {
    __builtin_amdgcn_global_load_lds(
        (const __attribute__((address_space(1))) unsigned int*)g,
        (__attribute__((address_space(3))) unsigned int*)l, 16, 0, 0);
}

// ---------------------------------------------------------------------------
// Weight prep: split Wg, Wc (fp32 [D,D]) into bf16 hi/lo planes.
// ---------------------------------------------------------------------------
__global__ __launch_bounds__(256) void wprep_kernel(
    const float* __restrict__ Wg, const float* __restrict__ Wc,
    unsigned short* __restrict__ Wghi, unsigned short* __restrict__ Wglo,
    unsigned short* __restrict__ Wchi, unsigned short* __restrict__ Wclo)
{
    int idx = (blockIdx.x * 256 + threadIdx.x) * 4;  // over 2*D*D elements
    const int n = D_ * D_;
    const float* src; unsigned short *dh, *dl; int o;
    if (idx < n) { src = Wg; dh = Wghi; dl = Wglo; o = idx; }
    else         { src = Wc; dh = Wchi; dl = Wclo; o = idx - n; }
    float4 v = *(const float4*)(src + o);
    ushort4 hi, lo;
    hi.x = f2bf(v.x); lo.x = f2bf(v.x - bf2f(hi.x));
    hi.y = f2bf(v.y); lo.y = f2bf(v.y - bf2f(hi.y));
    hi.z = f2bf(v.z); lo.z = f2bf(v.z - bf2f(hi.z));
    hi.w = f2bf(v.w); lo.w = f2bf(v.w - bf2f(hi.w));
    *(ushort4*)(dh + o) = hi;
    *(ushort4*)(dl + o) = lo;
}

// ---------------------------------------------------------------------------
// Fused dual GEMM + activation via split-bf16 MFMA.
//   z = x@W^T + b;  g = sigmoid(z) or c = tanh(z)
// grid = (M/128, 16): y<8 -> gate (Wg), y>=8 -> candidate (Wc).
// Per block: 128x128 out tile; 4 waves, each 64x64 = 4x4 frags of 16x16.
// A (x) staged fp32->hi/lo in-register -> ds_write; B (W) via global_load_lds
// from pre-split hi/lo planes. 48 MFMA per BK=32 step (hh, hl, lh).
// ---------------------------------------------------------------------------
__global__ __launch_bounds__(256) void gemm_mfma_kernel(
    const float* __restrict__ X,
    const unsigned short* __restrict__ Wghi, const unsigned short* __restrict__ Wglo,
    const unsigned short* __restrict__ Wchi, const unsigned short* __restrict__ Wclo,
    const float* __restrict__ bg, const float* __restrict__ bc,
    float* __restrict__ g_ws, float* __restrict__ c_ws)
{
    __shared__ __align__(16) unsigned short sAhi[BM * BK];  // 8 KB each
    __shared__ __align__(16) unsigned short sAlo[BM * BK];
    __shared__ __align__(16) unsigned short sBhi[BN * BK];
    __shared__ __align__(16) unsigned short sBlo[BN * BK];

    const int t = threadIdx.x;
    const int lane = t & 63;
    const int w = t >> 6;          // wave 0..3
    const int wrow = w >> 1;       // 0..1
    const int wcol = w & 1;        // 0..1
    const int quad = lane >> 4;    // 0..3
    const int l16  = lane & 15;

    const int mblk = blockIdx.x;
    const int nblk = blockIdx.y;
    const bool isGate = (nblk < 8);
    const unsigned short* __restrict__ Whi = isGate ? Wghi : Wchi;
    const unsigned short* __restrict__ Wlo = isGate ? Wglo : Wclo;
    const float* __restrict__ bias = isGate ? bg : bc;
    float* __restrict__ outp       = isGate ? g_ws : c_ws;
    const int n0 = (nblk & 7) * BN;
    const int m0 = mblk * BM;

    f32x4 acc[4][4] = {};

#pragma unroll 1
    for (int k0 = 0; k0 < K_; k0 += BK) {
        __syncthreads();   // all waves done reading previous tiles

        // ---- B staging: async DMA from pre-split bf16 planes ----
        // 8 KB tile = 2 passes of 256 threads x 16 B. LDS layout [128][32] bf16.
#pragma unroll
        for (int p = 0; p < 2; ++p) {
            int o   = t * 16 + p * 4096;       // byte offset in tile
            int row = o >> 6;                  // 64 B per row
            int kc  = (o & 63) >> 1;           // element offset in k (0,8,16,24)
            const unsigned short* srcH = Whi + (size_t)(n0 + row) * K_ + k0 + kc;
            const unsigned short* srcL = Wlo + (size_t)(n0 + row) * K_ + k0 + kc;
            async16(srcH, (char*)sBhi + o);
            async16(srcL, (char*)sBlo + o);
        }

        // ---- A staging: fp32 load -> split -> ds_write ----
        // 128x32 elements = 4 passes of 256 threads x float4.
#pragma unroll
        for (int p = 0; p < 4; ++p) {
            int idx = (p * 256 + t) * 4;
            int row = idx >> 5;                // 32 k per row
            int k   = idx & 31;
            float4 v = *(const float4*)(X + (size_t)(m0 + row) * K_ + k0 + k);
            ushort4 hi, lo;
            hi.x = f2bf(v.x); lo.x = f2bf(v.x - bf2f(hi.x));
            hi.y = f2bf(v.y); lo.y = f2bf(v.y - bf2f(hi.y));
            hi.z = f2bf(v.z); lo.z = f2bf(v.z - bf2f(hi.z));
            hi.w = f2bf(v.w); lo.w = f2bf(v.w - bf2f(hi.w));
            *(ushort4*)(sAhi + row * BK + k) = hi;
            *(ushort4*)(sAlo + row * BK + k) = lo;
        }

        __syncthreads();   // drains vmcnt (DMA) + lgkmcnt (ds_write)

        // ---- fragment loads + MFMA ----
        bf16x8 ahi[4], alo[4];
#pragma unroll
        for (int i = 0; i < 4; ++i) {
            int off = (wrow * 64 + i * 16 + l16) * BK + quad * 8;
            ahi[i] = *(const bf16x8*)(sAhi + off);
            alo[i] = *(const bf16x8*)(sAlo + off);
        }
#pragma unroll
        for (int j = 0; j < 4; ++j) {
            int off = (wcol * 64 + j * 16 + l16) * BK + quad * 8;
            bf16x8 bhi = *(const bf16x8*)(sBhi + off);
            bf16x8 blo = *(const bf16x8*)(sBlo + off);
#pragma unroll
            for (int i = 0; i < 4; ++i) {
                acc[i][j] = __builtin_amdgcn_mfma_f32_16x16x32_bf16(ahi[i], bhi, acc[i][j], 0, 0, 0);
                acc[i][j] = __builtin_amdgcn_mfma_f32_16x16x32_bf16(ahi[i], blo, acc[i][j], 0, 0, 0);
                acc[i][j] = __builtin_amdgcn_mfma_f32_16x16x32_bf16(alo[i], bhi, acc[i][j], 0, 0, 0);
            }
        }
    }

    // ---- epilogue: bias + activation + store ----
    // C/D layout: col = lane&15, row = quad*4 + reg  [m89-verified]
#pragma unroll
    for (int j = 0; j < 4; ++j) {
        int n = n0 + wcol * 64 + j * 16 + l16;
        float bv = bias[n];
#pragma unroll
        for (int i = 0; i < 4; ++i) {
#pragma unroll
            for (int r = 0; r < 4; ++r) {
                int m = m0 + wrow * 64 + i * 16 + quad * 4 + r;
                float z = acc[i][j][r] + bv;
                float vv = isGate ? (1.f / (1.f + __expf(-z))) : tanhf(z);
                outp[(size_t)m * D_ + n] = vv;
            }
        }
    }
}

// ---------------------------------------------------------------------------
// Kernel 2: per-chunk local scan -> chunk carry (A = prod g, Bv = local h end)
// ---------------------------------------------------------------------------
__global__ __launch_bounds__(256) void scan_phase1(
    const float* __restrict__ g_ws, const float* __restrict__ c_ws,
    float* __restrict__ carryA, float* __restrict__ carryB)
{
    const int t = threadIdx.x;
    const int cid = blockIdx.x;
    const int b   = blockIdx.y;
    const size_t base = ((size_t)b * L_ + (size_t)cid * CHUNK) * D_;
    const float4* g4 = (const float4*)(g_ws + base) + t;
    const float4* c4 = (const float4*)(c_ws + base) + t;

    float4 A  = make_float4(1.f, 1.f, 1.f, 1.f);
    float4 Bv = make_float4(0.f, 0.f, 0.f, 0.f);
#pragma unroll 4
    for (int l = 0; l < CHUNK; ++l) {
        float4 g = g4[(size_t)l * (D_ / 4)];
        float4 c = c4[(size_t)l * (D_ / 4)];
        Bv.x = fmaf(g.x, Bv.x, c.x); Bv.y = fmaf(g.y, Bv.y, c.y);
        Bv.z = fmaf(g.z, Bv.z, c.z); Bv.w = fmaf(g.w, Bv.w, c.w);
        A.x *= g.x; A.y *= g.y; A.z *= g.z; A.w *= g.w;
    }
    const size_t cbase = ((size_t)b * NC + cid) * D_;
    ((float4*)(carryA + cbase))[t] = A;
    ((float4*)(carryB + cbase))[t] = Bv;
}

// ---------------------------------------------------------------------------
// Kernel 3: exclusive scan of chunk carries; carryB[k] <- h entering chunk k.
// ---------------------------------------------------------------------------
__global__ __launch_bounds__(256) void scan_phase2(
    const float* __restrict__ carryA, float* __restrict__ carryB)
{
    const int idx = blockIdx.x * 256 + threadIdx.x;
    const int b = idx >> 10;
    const int d = idx & (D_ - 1);
    float accB = 0.f;
    for (int k = 0; k < NC; ++k) {
        const size_t o = ((size_t)b * NC + k) * D_ + d;
        const float a  = carryA[o];
        const float bb = carryB[o];
        carryB[o] = accB;
        accB = fmaf(a, accB, bb);
    }
}

// ---------------------------------------------------------------------------
// Kernel 4: re-scan each chunk with its incoming h, write final output.
// ---------------------------------------------------------------------------
__global__ __launch_bounds__(256) void scan_phase3(
    const float* __restrict__ g_ws, const float* __restrict__ c_ws,
    const float* __restrict__ carryB, float* __restrict__ out)
{
    const int t = threadIdx.x;
    const int cid = blockIdx.x;
    const int b   = blockIdx.y;
    const size_t base = ((size_t)b * L_ + (size_t)cid * CHUNK) * D_;
    const float4* g4 = (const float4*)(g_ws + base) + t;
    const float4* c4 = (const float4*)(c_ws + base) + t;
    float4* o4 = (float4*)(out + base) + t;

    const size_t cbase = ((size_t)b * NC + cid) * D_;
    float4 h = ((const float4*)(carryB + cbase))[t];
#pragma unroll 4
    for (int l = 0; l < CHUNK; ++l) {
        float4 g = g4[(size_t)l * (D_ / 4)];
        float4 c = c4[(size_t)l * (D_ / 4)];
        h.x = fmaf(g.x, h.x, c.x); h.y = fmaf(g.y, h.y, c.y);
        h.z = fmaf(g.z, h.z, c.z); h.w = fmaf(g.w, h.w, c.w);
        o4[(size_t)l * (D_ / 4)] = h;
    }
}

// ---------------------------------------------------------------------------
extern "C" void kernel_launch(void* const* d_in, const int* in_sizes, int n_in,
                              void* d_out, int out_size, void* d_ws, size_t ws_size,
                              hipStream_t stream)
{
    const float* x  = (const float*)d_in[0];
    const float* Wg = (const float*)d_in[1];
    const float* bg = (const float*)d_in[2];
    const float* Wc = (const float*)d_in[3];
    const float* bc = (const float*)d_in[4];
    float* out = (float*)d_out;

    // Workspace layout:
    //   g_ws   fp32 M*D      134.2 MB
    //   c_ws   fp32 M*D      134.2 MB
    //   carryA fp32 B*NC*D     2 MB
    //   carryB fp32 B*NC*D     2 MB
    //   Wghi/Wglo/Wchi/Wclo  bf16 D*D  2 MB each  (total ~281 MB)
    float* ws = (float*)d_ws;
    float* g_ws   = ws;
    float* c_ws   = g_ws + (size_t)M_ * D_;
    float* carryA = c_ws + (size_t)M_ * D_;
    float* carryB = carryA + (size_t)B_ * NC * D_;
    unsigned short* Wghi = (unsigned short*)(carryB + (size_t)B_ * NC * D_);
    unsigned short* Wglo = Wghi + (size_t)D_ * D_;
    unsigned short* Wchi = Wglo + (size_t)D_ * D_;
    unsigned short* Wclo = Wchi + (size_t)D_ * D_;

    wprep_kernel<<<(2 * D_ * D_ / 4) / 256, 256, 0, stream>>>(
        Wg, Wc, Wghi, Wglo, Wchi, Wclo);

    dim3 ggrid(M_ / BM, 16);
    gemm_mfma_kernel<<<ggrid, 256, 0, stream>>>(
        x, Wghi, Wglo, Wchi, Wclo, bg, bc, g_ws, c_ws);

    scan_phase1<<<dim3(NC, B_), 256, 0, stream>>>(g_ws, c_ws, carryA, carryB);
    scan_phase2<<<(B_ * D_) / 256, 256, 0, stream>>>(carryA, carryB);
    scan_phase3<<<dim3(NC, B_), 256, 0, stream>>>(g_ws, c_ws, carryB, out);
}